// Round 12
// baseline (125.019 us; speedup 1.0000x reference)
//
#include <hip/hip_runtime.h>
#include <math.h>

#define K_CODES 512
#define D_DIM   64
#define BM      128        // points per block (pass 1)
#define NCHUNK  128        // codes per LDS chunk
#define THREADS 256
#define LSTR    72         // padded LDS row stride (ushorts): 64 + 8 -> <=2-way banks
#define EPS_GAP 1e-4f      // certification margin (ref grid noise ~8e-6, 12x safety)

typedef __attribute__((ext_vector_type(8))) short short8v;  // 8 bf16 (4 VGPRs)
typedef __attribute__((ext_vector_type(4))) float f32x4;

// ---------- FROZEN numerics (bit-exact vs np reference since R3) ----------
__device__ __forceinline__ float np_sumsq64(const float* zarr) {
    float L[16];
#pragma unroll
    for (int j = 0; j < 16; ++j)
        L[j] = __fadd_rn(
            __fadd_rn(__fmul_rn(zarr[j],      zarr[j]),
                      __fmul_rn(zarr[j + 16], zarr[j + 16])),
            __fadd_rn(__fmul_rn(zarr[j + 32], zarr[j + 32]),
                      __fmul_rn(zarr[j + 48], zarr[j + 48])));
    float m[8];
#pragma unroll
    for (int j = 0; j < 8; ++j) m[j] = __fadd_rn(L[j], L[j + 8]);
    float n4[4];
#pragma unroll
    for (int j = 0; j < 4; ++j) n4[j] = __fadd_rn(m[j], m[j + 4]);
    return __fadd_rn(__fadd_rn(n4[0], n4[2]), __fadd_rn(n4[1], n4[3]));
}

__global__ __launch_bounds__(256) void vq_norms_kernel(const float* __restrict__ cb,
                                                       float* __restrict__ norms) {
    int k = blockIdx.x * blockDim.x + threadIdx.x;
    if (k >= K_CODES) return;
    float e[D_DIM];
    const float4* p = reinterpret_cast<const float4*>(cb + (size_t)k * D_DIM);
#pragma unroll
    for (int i = 0; i < 16; ++i) {
        float4 v = p[i];
        e[4*i+0]=v.x; e[4*i+1]=v.y; e[4*i+2]=v.z; e[4*i+3]=v.w;
    }
    norms[k] = np_sumsq64(e);
}

// ---------- bf16 split helpers (exact: x = hi + lo + r, |r| <= 2^-18|x|) ----------
__device__ __forceinline__ unsigned short f32_bf16_rne(float x) {
    unsigned int u = __float_as_uint(x);
    unsigned int r = (u + 0x7FFFu + ((u >> 16) & 1u)) >> 16;
    return (unsigned short)r;
}
__device__ __forceinline__ float bf16_f32(unsigned short h) {
    return __uint_as_float(((unsigned int)h) << 16);
}
__device__ __forceinline__ void split2(float x, unsigned short& h, unsigned short& l) {
    h = f32_bf16_rne(x);
    l = f32_bf16_rne(x - bf16_f32(h));   // x - hi is exact in fp32
}

// ---------- Pass 1: MFMA split-bf16 GEMM-argmin with min1/min2 certification ----------
// UNCHANGED from R11 (bit-identical). Counters said its cleanup partner, not
// pass1, ate the time (pass1 absent from top-5; cleanup 77us VGPR=256 spill).
__global__ __launch_bounds__(256)
void vq_pass1_kernel(const float* __restrict__ z, const float* __restrict__ cb,
                     const float* __restrict__ norms, int* __restrict__ out, int n) {
    __shared__ unsigned short zhS[BM * LSTR];      // 18 KB each
    __shared__ unsigned short zlS[BM * LSTR];
    __shared__ unsigned short ehS[NCHUNK * LSTR];
    __shared__ unsigned short elS[NCHUNK * LSTR];
    __shared__ float nrmL[NCHUNK];                 // 74.2 KB total -> 2 blocks/CU

    const int tid  = threadIdx.x;
    const int l    = tid & 63;
    const int w    = tid >> 6;        // wave 0..3 -> point-tiles {2w, 2w+1}
    const int j    = l >> 4;          // k-chunk / C-row-group selector 0..3
    const int c16  = l & 15;
    const int base = blockIdx.x * BM;

    // ---- stage z -> hi/lo bf16 (coalesced float4 reads, once per block) ----
    const float4* z4 = reinterpret_cast<const float4*>(z);
#pragma unroll
    for (int rep = 0; rep < 8; ++rep) {
        int flat = rep * THREADS + tid;            // 0..2047
        int pt   = flat >> 4;
        int dblk = flat & 15;
        int gp = base + pt; if (gp >= n) gp = n - 1;
        float4 v = z4[(size_t)gp * 16 + dblk];
        ushort4 h, lo;
        split2(v.x, h.x, lo.x); split2(v.y, h.y, lo.y);
        split2(v.z, h.z, lo.z); split2(v.w, h.w, lo.w);
        *reinterpret_cast<ushort4*>(&zhS[pt * LSTR + dblk * 4]) = h;
        *reinterpret_cast<ushort4*>(&zlS[pt * LSTR + dblk * 4]) = lo;
    }
    __syncthreads();

    // ---- hoist this wave's z (B) fragments: 2 pt-tiles x hi/lo x 2 K-halves ----
    short8v bzh[2][2], bzl[2][2];
#pragma unroll
    for (int p = 0; p < 2; ++p) {
        int pr = ((2 * w + p) * 16 + c16) * LSTR;
#pragma unroll
        for (int h = 0; h < 2; ++h) {
            int off = pr + h * 32 + j * 8;
            bzh[p][h] = *reinterpret_cast<const short8v*>(&zhS[off]);
            bzl[p][h] = *reinterpret_cast<const short8v*>(&zlS[off]);
        }
    }

    float m1[2] = {INFINITY, INFINITY};
    float m2[2] = {INFINITY, INFINITY};
    int   i1[2] = {0, 0};

    for (int c = 0; c < 4; ++c) {
        __syncthreads();   // previous chunk's e-tiles consumed
        const float4* cb4 = reinterpret_cast<const float4*>(cb);
#pragma unroll
        for (int rep = 0; rep < 8; ++rep) {
            int flat = rep * THREADS + tid;
            int code = flat >> 4;
            int dblk = flat & 15;
            float4 v = cb4[(size_t)(c * NCHUNK + code) * 16 + dblk];
            ushort4 h, lo;
            split2(v.x, h.x, lo.x); split2(v.y, h.y, lo.y);
            split2(v.z, h.z, lo.z); split2(v.w, h.w, lo.w);
            *reinterpret_cast<ushort4*>(&ehS[code * LSTR + dblk * 4]) = h;
            *reinterpret_cast<ushort4*>(&elS[code * LSTR + dblk * 4]) = lo;
        }
        if (tid < NCHUNK / 4)
            reinterpret_cast<float4*>(nrmL)[tid] =
                reinterpret_cast<const float4*>(norms)[c * (NCHUNK / 4) + tid];
        __syncthreads();

#pragma unroll
        for (int ct = 0; ct < 8; ++ct) {
            int ar = (ct * 16 + c16) * LSTR + j * 8;
            short8v aeh0 = *reinterpret_cast<const short8v*>(&ehS[ar]);
            short8v aeh1 = *reinterpret_cast<const short8v*>(&ehS[ar + 32]);
            short8v ael0 = *reinterpret_cast<const short8v*>(&elS[ar]);
            short8v ael1 = *reinterpret_cast<const short8v*>(&elS[ar + 32]);
            float4 nr = *reinterpret_cast<const float4*>(&nrmL[ct * 16 + j * 4]);
            float nra[4] = {nr.x, nr.y, nr.z, nr.w};
            int kg0 = c * NCHUNK + ct * 16 + j * 4;
#pragma unroll
            for (int p = 0; p < 2; ++p) {
                f32x4 acc = {0.f, 0.f, 0.f, 0.f};
                acc = __builtin_amdgcn_mfma_f32_16x16x32_bf16(aeh0, bzh[p][0], acc, 0, 0, 0);
                acc = __builtin_amdgcn_mfma_f32_16x16x32_bf16(aeh1, bzh[p][1], acc, 0, 0, 0);
                acc = __builtin_amdgcn_mfma_f32_16x16x32_bf16(aeh0, bzl[p][0], acc, 0, 0, 0);
                acc = __builtin_amdgcn_mfma_f32_16x16x32_bf16(aeh1, bzl[p][1], acc, 0, 0, 0);
                acc = __builtin_amdgcn_mfma_f32_16x16x32_bf16(ael0, bzh[p][0], acc, 0, 0, 0);
                acc = __builtin_amdgcn_mfma_f32_16x16x32_bf16(ael1, bzh[p][1], acc, 0, 0, 0);
#pragma unroll
                for (int r = 0; r < 4; ++r) {
                    float s = fmaf(-2.0f, acc[r], nra[r]);   // accuracy-only path
                    int kg = kg0 + r;
                    bool lt1 = s < m1[p];
                    float nm2 = lt1 ? m1[p] : fminf(s, m2[p]);
                    i1[p] = lt1 ? kg : i1[p];
                    m1[p] = lt1 ? s : m1[p];
                    m2[p] = nm2;
                }
            }
        }
    }

    // ---- butterfly merge across the 4 row-groups (lanes l, l^16, l^32) ----
#pragma unroll
    for (int p = 0; p < 2; ++p) {
        float a1 = m1[p], a2 = m2[p]; int ai = i1[p];
#pragma unroll
        for (int off = 16; off <= 32; off <<= 1) {
            float o1 = __shfl_xor(a1, off, 64);
            float o2 = __shfl_xor(a2, off, 64);
            int   oi = __shfl_xor(ai, off, 64);
            float hi = fmaxf(a1, o1);
            bool take = o1 < a1;                 // ties keep own (tie => flagged anyway)
            ai = take ? oi : ai;
            a1 = take ? o1 : a1;
            a2 = fminf(hi, fminf(a2, o2));
        }
        if (j == 0) {
            int ptg = base + (2 * w + p) * 16 + c16;
            if (ptg < n)
                out[ptg] = ai | ((a2 - a1 <= EPS_GAP) ? (int)0x80000000 : 0);
        }
    }
}

// ---------- Pass 2: wave-cooperative FROZEN rescan of flagged points ----------
// R12 fix: R11's version fully unrolled 8x64 loads+FMAs -> scheduler hoisted
// ~512 loads, VGPR=256 + per-LANE zr spill (256B x 64 lanes = 16KB scratch
// round-trip per flagged point = the 26 MB WRITE_SIZE / 77us at 0% VALU).
// Now: sequential r-loop (unroll 1), one float4 e-buffer in flight, live set
// ~95 regs -> no spill. FROZEN chain order unchanged (scalar ascending-d).
__global__ __launch_bounds__(256)
void vq_cleanup_kernel(const float* __restrict__ z, const float* __restrict__ cb,
                       const float* __restrict__ norms, int* __restrict__ out, int n) {
    const int lane  = threadIdx.x & 63;
    const int wid   = blockIdx.x * (blockDim.x >> 6) + (threadIdx.x >> 6);
    const int tbase = wid * 64;
    if (tbase >= n) return;
    int t = tbase + lane;
    int v = (t < n) ? out[t] : 0;
    unsigned long long mask = __ballot(v < 0);
    while (mask) {
        int b = __ffsll(mask) - 1;
        mask &= mask - 1;
        int pt = tbase + b;
        float zr[D_DIM];
        const float4* zp = reinterpret_cast<const float4*>(z + (size_t)pt * D_DIM);
#pragma unroll
        for (int i = 0; i < 16; ++i) {
            float4 q = zp[i];
            zr[4*i+0]=q.x; zr[4*i+1]=q.y; zr[4*i+2]=q.z; zr[4*i+3]=q.w;
        }
        const float sz = np_sumsq64(zr);           // FROZEN tree
        float best = INFINITY; int bi = 0x7FFFFFFF;
#pragma unroll 1
        for (int r = 0; r < 8; ++r) {              // 8 codes/lane, SEQUENTIAL
            const float4* e4 = reinterpret_cast<const float4*>(cb) +
                               ((size_t)(lane * 8 + r) << 4);
            float a = 0.f;
#pragma unroll
            for (int g = 0; g < 16; ++g) {         // FROZEN ascending-d chain
                float4 q = e4[g];
                a = fmaf(zr[4*g+0], q.x, a);
                a = fmaf(zr[4*g+1], q.y, a);
                a = fmaf(zr[4*g+2], q.z, a);
                a = fmaf(zr[4*g+3], q.w, a);
            }
            float s = __fadd_rn(__fsub_rn(sz, __fmul_rn(2.0f, a)),
                                norms[lane * 8 + r]);
            if (s < best) { best = s; bi = lane * 8 + r; }
        }
#pragma unroll
        for (int off = 1; off < 64; off <<= 1) {   // (value, index) first-min reduce
            float os = __shfl_xor(best, off, 64);
            int   ok = __shfl_xor(bi, off, 64);
            if (os < best || (os == best && ok < bi)) { best = os; bi = ok; }
        }
        if (lane == 0) out[pt] = bi;
    }
}

extern "C" void kernel_launch(void* const* d_in, const int* in_sizes, int n_in,
                              void* d_out, int out_size, void* d_ws, size_t ws_size,
                              hipStream_t stream) {
    const float* z  = (const float*)d_in[0];
    const float* cb = (const float*)d_in[1];
    int n = in_sizes[0] / D_DIM;           // 131072 points
    float* norms = (float*)d_ws;           // 512 floats of scratch
    int* out = (int*)d_out;

    vq_norms_kernel<<<(K_CODES + 255) / 256, 256, 0, stream>>>(cb, norms);
    vq_pass1_kernel<<<(n + BM - 1) / BM, THREADS, 0, stream>>>(z, cb, norms, out, n);
    vq_cleanup_kernel<<<(n + 255) / 256, 256, 0, stream>>>(z, cb, norms, out, n);
}

// Round 13
// 67.611 us; speedup vs baseline: 1.8491x; 1.8491x over previous
//
#include <hip/hip_runtime.h>
#include <math.h>

#define K_CODES 512
#define D_DIM   64
#define BM      128        // points per block (pass 1)
#define NCHUNK  128        // codes per LDS chunk
#define THREADS 256
#define LSTR    72         // padded LDS row stride (ushorts): 64 + 8 -> <=2-way banks
#define EPS_GAP 4e-5f      // certified: 2*(dref~8e-6 + dacc~2e-6)=2e-5, 2x margin

typedef __attribute__((ext_vector_type(8))) short short8v;  // 8 bf16 (4 VGPRs)
typedef __attribute__((ext_vector_type(4))) float f32x4;

// ---------- FROZEN numerics (bit-exact vs np reference since R3) ----------
__device__ __forceinline__ float np_sumsq64(const float* zarr) {
    float L[16];
#pragma unroll
    for (int j = 0; j < 16; ++j)
        L[j] = __fadd_rn(
            __fadd_rn(__fmul_rn(zarr[j],      zarr[j]),
                      __fmul_rn(zarr[j + 16], zarr[j + 16])),
            __fadd_rn(__fmul_rn(zarr[j + 32], zarr[j + 32]),
                      __fmul_rn(zarr[j + 48], zarr[j + 48])));
    float m[8];
#pragma unroll
    for (int j = 0; j < 8; ++j) m[j] = __fadd_rn(L[j], L[j + 8]);
    float n4[4];
#pragma unroll
    for (int j = 0; j < 4; ++j) n4[j] = __fadd_rn(m[j], m[j + 4]);
    return __fadd_rn(__fadd_rn(n4[0], n4[2]), __fadd_rn(n4[1], n4[3]));
}

// norms + zero the compaction counter (runs before pass1, stream-ordered)
__global__ __launch_bounds__(256) void vq_norms_kernel(const float* __restrict__ cb,
                                                       float* __restrict__ ws) {
    int k = blockIdx.x * blockDim.x + threadIdx.x;
    if (k == 0) reinterpret_cast<int*>(ws)[512] = 0;   // flag counter
    if (k >= K_CODES) return;
    float e[D_DIM];
    const float4* p = reinterpret_cast<const float4*>(cb + (size_t)k * D_DIM);
#pragma unroll
    for (int i = 0; i < 16; ++i) {
        float4 v = p[i];
        e[4*i+0]=v.x; e[4*i+1]=v.y; e[4*i+2]=v.z; e[4*i+3]=v.w;
    }
    ws[k] = np_sumsq64(e);
}

// ---------- bf16 split helpers (exact: x = hi + lo + r, |r| <= 2^-18|x|) ----------
__device__ __forceinline__ unsigned short f32_bf16_rne(float x) {
    unsigned int u = __float_as_uint(x);
    unsigned int r = (u + 0x7FFFu + ((u >> 16) & 1u)) >> 16;
    return (unsigned short)r;
}
__device__ __forceinline__ float bf16_f32(unsigned short h) {
    return __uint_as_float(((unsigned int)h) << 16);
}
__device__ __forceinline__ void split2(float x, unsigned short& h, unsigned short& l) {
    h = f32_bf16_rne(x);
    l = f32_bf16_rne(x - bf16_f32(h));   // x - hi is exact in fp32
}

// ---------- Pass 1: MFMA split-bf16 GEMM-argmin, min1/min2 certification ----------
// Compute identical to R11/R12. Epilogue now COMPACTS flagged points into a
// worklist (ballot + 1 atomicAdd/wave) so cleanup can load-balance; bit-31
// flag in out[] only as list-overflow fallback.
__global__ __launch_bounds__(256)
void vq_pass1_kernel(const float* __restrict__ z, const float* __restrict__ cb,
                     const float* __restrict__ norms, int* __restrict__ out,
                     int* __restrict__ cnt, int* __restrict__ list, int cap, int n) {
    __shared__ unsigned short zhS[BM * LSTR];      // 18 KB each
    __shared__ unsigned short zlS[BM * LSTR];
    __shared__ unsigned short ehS[NCHUNK * LSTR];
    __shared__ unsigned short elS[NCHUNK * LSTR];
    __shared__ float nrmL[NCHUNK];                 // 74.2 KB total -> 2 blocks/CU

    const int tid  = threadIdx.x;
    const int l    = tid & 63;
    const int w    = tid >> 6;        // wave 0..3 -> point-tiles {2w, 2w+1}
    const int j    = l >> 4;          // k-chunk / C-row-group selector 0..3
    const int c16  = l & 15;
    const int base = blockIdx.x * BM;

    // ---- stage z -> hi/lo bf16 (coalesced float4 reads, once per block) ----
    const float4* z4 = reinterpret_cast<const float4*>(z);
#pragma unroll
    for (int rep = 0; rep < 8; ++rep) {
        int flat = rep * THREADS + tid;            // 0..2047
        int pt   = flat >> 4;
        int dblk = flat & 15;
        int gp = base + pt; if (gp >= n) gp = n - 1;
        float4 v = z4[(size_t)gp * 16 + dblk];
        ushort4 h, lo;
        split2(v.x, h.x, lo.x); split2(v.y, h.y, lo.y);
        split2(v.z, h.z, lo.z); split2(v.w, h.w, lo.w);
        *reinterpret_cast<ushort4*>(&zhS[pt * LSTR + dblk * 4]) = h;
        *reinterpret_cast<ushort4*>(&zlS[pt * LSTR + dblk * 4]) = lo;
    }
    __syncthreads();

    // ---- hoist this wave's z (B) fragments: 2 pt-tiles x hi/lo x 2 K-halves ----
    short8v bzh[2][2], bzl[2][2];
#pragma unroll
    for (int p = 0; p < 2; ++p) {
        int pr = ((2 * w + p) * 16 + c16) * LSTR;
#pragma unroll
        for (int h = 0; h < 2; ++h) {
            int off = pr + h * 32 + j * 8;
            bzh[p][h] = *reinterpret_cast<const short8v*>(&zhS[off]);
            bzl[p][h] = *reinterpret_cast<const short8v*>(&zlS[off]);
        }
    }

    float m1[2] = {INFINITY, INFINITY};
    float m2[2] = {INFINITY, INFINITY};
    int   i1[2] = {0, 0};

    for (int c = 0; c < 4; ++c) {
        __syncthreads();   // previous chunk's e-tiles consumed
        const float4* cb4 = reinterpret_cast<const float4*>(cb);
#pragma unroll
        for (int rep = 0; rep < 8; ++rep) {
            int flat = rep * THREADS + tid;
            int code = flat >> 4;
            int dblk = flat & 15;
            float4 v = cb4[(size_t)(c * NCHUNK + code) * 16 + dblk];
            ushort4 h, lo;
            split2(v.x, h.x, lo.x); split2(v.y, h.y, lo.y);
            split2(v.z, h.z, lo.z); split2(v.w, h.w, lo.w);
            *reinterpret_cast<ushort4*>(&ehS[code * LSTR + dblk * 4]) = h;
            *reinterpret_cast<ushort4*>(&elS[code * LSTR + dblk * 4]) = lo;
        }
        if (tid < NCHUNK / 4)
            reinterpret_cast<float4*>(nrmL)[tid] =
                reinterpret_cast<const float4*>(norms)[c * (NCHUNK / 4) + tid];
        __syncthreads();

#pragma unroll
        for (int ct = 0; ct < 8; ++ct) {
            int ar = (ct * 16 + c16) * LSTR + j * 8;
            short8v aeh0 = *reinterpret_cast<const short8v*>(&ehS[ar]);
            short8v aeh1 = *reinterpret_cast<const short8v*>(&ehS[ar + 32]);
            short8v ael0 = *reinterpret_cast<const short8v*>(&elS[ar]);
            short8v ael1 = *reinterpret_cast<const short8v*>(&elS[ar + 32]);
            float4 nr = *reinterpret_cast<const float4*>(&nrmL[ct * 16 + j * 4]);
            float nra[4] = {nr.x, nr.y, nr.z, nr.w};
            int kg0 = c * NCHUNK + ct * 16 + j * 4;
#pragma unroll
            for (int p = 0; p < 2; ++p) {
                f32x4 acc = {0.f, 0.f, 0.f, 0.f};
                acc = __builtin_amdgcn_mfma_f32_16x16x32_bf16(aeh0, bzh[p][0], acc, 0, 0, 0);
                acc = __builtin_amdgcn_mfma_f32_16x16x32_bf16(aeh1, bzh[p][1], acc, 0, 0, 0);
                acc = __builtin_amdgcn_mfma_f32_16x16x32_bf16(aeh0, bzl[p][0], acc, 0, 0, 0);
                acc = __builtin_amdgcn_mfma_f32_16x16x32_bf16(aeh1, bzl[p][1], acc, 0, 0, 0);
                acc = __builtin_amdgcn_mfma_f32_16x16x32_bf16(ael0, bzh[p][0], acc, 0, 0, 0);
                acc = __builtin_amdgcn_mfma_f32_16x16x32_bf16(ael1, bzh[p][1], acc, 0, 0, 0);
#pragma unroll
                for (int r = 0; r < 4; ++r) {
                    float s = fmaf(-2.0f, acc[r], nra[r]);   // accuracy-only path
                    int kg = kg0 + r;
                    bool lt1 = s < m1[p];
                    float nm2 = lt1 ? m1[p] : fminf(s, m2[p]);
                    i1[p] = lt1 ? kg : i1[p];
                    m1[p] = lt1 ? s : m1[p];
                    m2[p] = nm2;
                }
            }
        }
    }

    // ---- butterfly merge + compacting store ----
#pragma unroll
    for (int p = 0; p < 2; ++p) {
        float a1 = m1[p], a2 = m2[p]; int ai = i1[p];
#pragma unroll
        for (int off = 16; off <= 32; off <<= 1) {
            float o1 = __shfl_xor(a1, off, 64);
            float o2 = __shfl_xor(a2, off, 64);
            int   oi = __shfl_xor(ai, off, 64);
            float hi = fmaxf(a1, o1);
            bool take = o1 < a1;                 // ties keep own (tie => flagged anyway)
            ai = take ? oi : ai;
            a1 = take ? o1 : a1;
            a2 = fminf(hi, fminf(a2, o2));
        }
        int  ptg    = base + (2 * w + p) * 16 + c16;
        bool writer = (j == 0) && (ptg < n);
        bool flag   = writer && (a2 - a1 <= EPS_GAP);
        unsigned long long m = __ballot(flag);   // all lanes reach this
        int abase = 0;
        if (m) {
            int leader = __ffsll(m) - 1;
            if (l == leader) abase = atomicAdd(cnt, __popcll(m));
            abase = __shfl(abase, leader, 64);
        }
        if (writer) {
            int val = ai;
            if (flag) {
                int rank = __popcll(m & ((1ull << l) - 1ull));
                int slot = abase + rank;
                if (slot < cap) list[slot] = ptg;       // worklist path
                else            val |= (int)0x80000000; // overflow fallback
            }
            out[ptg] = val;
        }
    }
}

// ---------- Pass 2: ONE WAVE PER FLAGGED POINT (grid-strided worklist) ----------
// R12 lesson: per-owner-wave serial rescans (ballot loop) made the slowest
// wave ~8 x 7us; the worklist parallelizes the same work across 2048 waves.
// Rescan is the FROZEN R3-exact path; (value,index) shfl reduce = first-min.
__device__ __forceinline__ void vq_rescan_point(
        const float* __restrict__ z, const float* __restrict__ cb,
        const float* __restrict__ norms, int* __restrict__ out,
        int pt, int lane) {
    float zr[D_DIM];
    const float4* zp = reinterpret_cast<const float4*>(z + (size_t)pt * D_DIM);
#pragma unroll
    for (int i = 0; i < 16; ++i) {
        float4 q = zp[i];
        zr[4*i+0]=q.x; zr[4*i+1]=q.y; zr[4*i+2]=q.z; zr[4*i+3]=q.w;
    }
    const float sz = np_sumsq64(zr);           // FROZEN tree
    float best = INFINITY; int bi = 0x7FFFFFFF;
#pragma unroll 1
    for (int r = 0; r < 8; ++r) {              // 8 codes/lane, SEQUENTIAL (no spill)
        const float4* e4 = reinterpret_cast<const float4*>(cb) +
                           ((size_t)(lane * 8 + r) << 4);
        float a = 0.f;
#pragma unroll
        for (int g = 0; g < 16; ++g) {         // FROZEN ascending-d chain
            float4 q = e4[g];
            a = fmaf(zr[4*g+0], q.x, a);
            a = fmaf(zr[4*g+1], q.y, a);
            a = fmaf(zr[4*g+2], q.z, a);
            a = fmaf(zr[4*g+3], q.w, a);
        }
        float s = __fadd_rn(__fsub_rn(sz, __fmul_rn(2.0f, a)),
                            norms[lane * 8 + r]);
        if (s < best) { best = s; bi = lane * 8 + r; }
    }
#pragma unroll
    for (int off = 1; off < 64; off <<= 1) {   // (value, index) first-min reduce
        float os = __shfl_xor(best, off, 64);
        int   ok = __shfl_xor(bi, off, 64);
        if (os < best || (os == best && ok < bi)) { best = os; bi = ok; }
    }
    if (lane == 0) out[pt] = bi;
}

__global__ __launch_bounds__(256)
void vq_cleanup_kernel(const float* __restrict__ z, const float* __restrict__ cb,
                       const float* __restrict__ norms,
                       const int* __restrict__ cnt, const int* __restrict__ list,
                       int cap, int* __restrict__ out, int n) {
    const int lane   = threadIdx.x & 63;
    const int wid    = (blockIdx.x * blockDim.x + threadIdx.x) >> 6;
    const int nwaves = (gridDim.x * blockDim.x) >> 6;

    int total = *cnt;
    int lim   = total < cap ? total : cap;
    for (int i = wid; i < lim; i += nwaves)
        vq_rescan_point(z, cb, norms, out, list[i], lane);

    if (total > cap) {   // overflow fallback: scan out[] for bit-31 flags
        for (int b = wid * 64; b < n; b += nwaves * 64) {
            int t = b + lane;
            int v = (t < n) ? out[t] : 0;
            unsigned long long m = __ballot(v < 0);
            while (m) {
                int bb = __ffsll(m) - 1;
                m &= m - 1ull;
                vq_rescan_point(z, cb, norms, out, b + bb, lane);
            }
        }
    }
}

extern "C" void kernel_launch(void* const* d_in, const int* in_sizes, int n_in,
                              void* d_out, int out_size, void* d_ws, size_t ws_size,
                              hipStream_t stream) {
    const float* z  = (const float*)d_in[0];
    const float* cb = (const float*)d_in[1];
    int n = in_sizes[0] / D_DIM;           // 131072 points
    float* norms = (float*)d_ws;           // ws[0..511]: norms
    int*   cnt   = (int*)d_ws + 512;       // ws[512]: flag counter
    int*   list  = (int*)d_ws + 513;       // ws[513..]: flagged-point worklist
    int    cap   = (int)(ws_size / 4) - 513;
    if (cap < 0) cap = 0;
    int* out = (int*)d_out;

    vq_norms_kernel<<<(K_CODES + 255) / 256, 256, 0, stream>>>(cb, norms);
    vq_pass1_kernel<<<(n + BM - 1) / BM, THREADS, 0, stream>>>(z, cb, norms, out,
                                                               cnt, list, cap, n);
    vq_cleanup_kernel<<<512, 256, 0, stream>>>(z, cb, norms, cnt, list, cap, out, n);
}

// Round 14
// 63.086 us; speedup vs baseline: 1.9817x; 1.0717x over previous
//
#include <hip/hip_runtime.h>
#include <math.h>

#define K_CODES 512
#define D_DIM   64
#define BM      128        // points per block (pass 1)
#define NCHUNK  128        // codes per LDS chunk
#define THREADS 256
#define LSTR    72         // padded row stride (ushorts): <=2-way banks on frag reads
#define EPS_GAP 4e-5f      // certified: 2*(dref~8e-6 + dacc~2e-6)=2e-5, 2x margin

// ws layout (bytes): [0,2048) norms f32[512] | [2048) cnt | [4096,77824) eh
// presplit bf16 [512][72] | [77824,151552) el | [151552,..) worklist
#define WS_CNT_OFF  2048
#define WS_EH_OFF   4096
#define WS_EL_OFF   77824
#define WS_LIST_OFF 151552

typedef __attribute__((ext_vector_type(8))) short short8v;  // 8 bf16 (4 VGPRs)
typedef __attribute__((ext_vector_type(4))) float f32x4;

// ---------- FROZEN numerics (bit-exact vs np reference since R3) ----------
__device__ __forceinline__ float np_sumsq64(const float* zarr) {
    float L[16];
#pragma unroll
    for (int j = 0; j < 16; ++j)
        L[j] = __fadd_rn(
            __fadd_rn(__fmul_rn(zarr[j],      zarr[j]),
                      __fmul_rn(zarr[j + 16], zarr[j + 16])),
            __fadd_rn(__fmul_rn(zarr[j + 32], zarr[j + 32]),
                      __fmul_rn(zarr[j + 48], zarr[j + 48])));
    float m[8];
#pragma unroll
    for (int j = 0; j < 8; ++j) m[j] = __fadd_rn(L[j], L[j + 8]);
    float n4[4];
#pragma unroll
    for (int j = 0; j < 4; ++j) n4[j] = __fadd_rn(m[j], m[j + 4]);
    return __fadd_rn(__fadd_rn(n4[0], n4[2]), __fadd_rn(n4[1], n4[3]));
}

// ---------- bf16 split helpers (exact: x = hi + lo + r, |r| <= 2^-18|x|) ----------
__device__ __forceinline__ unsigned short f32_bf16_rne(float x) {
    unsigned int u = __float_as_uint(x);
    unsigned int r = (u + 0x7FFFu + ((u >> 16) & 1u)) >> 16;
    return (unsigned short)r;
}
__device__ __forceinline__ float bf16_f32(unsigned short h) {
    return __uint_as_float(((unsigned int)h) << 16);
}
__device__ __forceinline__ void split2(float x, unsigned short& h, unsigned short& l) {
    h = f32_bf16_rne(x);
    l = f32_bf16_rne(x - bf16_f32(h));   // x - hi is exact in fp32
}

// ---------- prep: norms + counter zero + (optional) presplit codebook ----------
__global__ __launch_bounds__(256)
void vq_prep_kernel(const float* __restrict__ cb, float* __restrict__ ws,
                    int do_split) {
    int k = blockIdx.x * blockDim.x + threadIdx.x;
    if (k == 0) *reinterpret_cast<int*>((char*)ws + WS_CNT_OFF) = 0;
    if (k >= K_CODES) return;
    float e[D_DIM];
    const float4* p = reinterpret_cast<const float4*>(cb + (size_t)k * D_DIM);
#pragma unroll
    for (int i = 0; i < 16; ++i) {
        float4 v = p[i];
        e[4*i+0]=v.x; e[4*i+1]=v.y; e[4*i+2]=v.z; e[4*i+3]=v.w;
    }
    ws[k] = np_sumsq64(e);
    if (do_split) {
        unsigned short* eh = reinterpret_cast<unsigned short*>((char*)ws + WS_EH_OFF)
                             + (size_t)k * LSTR;
        unsigned short* el = reinterpret_cast<unsigned short*>((char*)ws + WS_EL_OFF)
                             + (size_t)k * LSTR;
#pragma unroll
        for (int i = 0; i < D_DIM; ++i) {
            unsigned short h, l;
            split2(e[i], h, l);              // EXACTLY the split pass1 used before
            eh[i] = h; el[i] = l;
        }
#pragma unroll
        for (int i = D_DIM; i < LSTR; ++i) { eh[i] = 0; el[i] = 0; }
    }
}

// ---------- Pass 1 FAST: presplit e via global_load_lds, z split in-register ----------
// R13 diagnosis: 49.8us at 17% occupancy (74KB LDS -> 2 blocks/CU) with ~40%
// of VALU burned re-splitting the codebook per block. Now: e-staging = pure
// DMA (no VALU), z B-frags wave-private -> loaded direct from global + split
// in-reg once. LDS 36.9KB -> 4 blocks/CU. MFMA inputs bit-identical to R13.
__global__ __launch_bounds__(256)
void vq_pass1_fast(const float* __restrict__ z,
                   const unsigned short* __restrict__ eh_g,
                   const unsigned short* __restrict__ el_g,
                   const float* __restrict__ norms, int* __restrict__ out,
                   int* __restrict__ cnt, int* __restrict__ list, int cap, int n) {
    __shared__ __align__(16) unsigned short ehS[NCHUNK * LSTR];  // 18 KB
    __shared__ __align__(16) unsigned short elS[NCHUNK * LSTR];  // 18 KB
    __shared__ float nrmL[NCHUNK];                               // 512 B

    const int tid  = threadIdx.x;
    const int l    = tid & 63;
    const int w    = tid >> 6;        // wave 0..3 -> point-tiles {2w, 2w+1}
    const int j    = l >> 4;          // k-chunk / C-row-group selector 0..3
    const int c16  = l & 15;
    const int base = blockIdx.x * BM;

    // ---- z B-fragments direct from global, split in-register (one-time) ----
    short8v bzh[2][2], bzl[2][2];
#pragma unroll
    for (int p = 0; p < 2; ++p) {
        int row = base + (2 * w + p) * 16 + c16;
        if (row >= n) row = n - 1;
        const float* zp = z + (size_t)row * D_DIM + j * 8;
#pragma unroll
        for (int h = 0; h < 2; ++h) {
            float4 v0 = *reinterpret_cast<const float4*>(zp + h * 32);
            float4 v1 = *reinterpret_cast<const float4*>(zp + h * 32 + 4);
            unsigned short hh[8], ll[8];
            split2(v0.x, hh[0], ll[0]); split2(v0.y, hh[1], ll[1]);
            split2(v0.z, hh[2], ll[2]); split2(v0.w, hh[3], ll[3]);
            split2(v1.x, hh[4], ll[4]); split2(v1.y, hh[5], ll[5]);
            split2(v1.z, hh[6], ll[6]); split2(v1.w, hh[7], ll[7]);
            short8v th, tl;
#pragma unroll
            for (int i = 0; i < 8; ++i) { th[i] = (short)hh[i]; tl[i] = (short)ll[i]; }
            bzh[p][h] = th; bzl[p][h] = tl;
        }
    }

    float m1[2] = {INFINITY, INFINITY};
    float m2[2] = {INFINITY, INFINITY};
    int   i1[2] = {0, 0};

    for (int c = 0; c < 4; ++c) {
        __syncthreads();   // previous chunk's e-tiles consumed
        {
            // chunk = 128 rows x 72 ushorts x 2B = 18432 B per buffer; pure DMA.
            const char* esrc = (const char*)eh_g + (size_t)c * (NCHUNK * LSTR * 2);
            const char* lsrc = (const char*)el_g + (size_t)c * (NCHUNK * LSTR * 2);
#pragma unroll
            for (int r2 = 0; r2 < 4; ++r2) {
                size_t off = ((size_t)tid + (size_t)r2 * 256) * 16;   // 16384 B
                __builtin_amdgcn_global_load_lds(
                    (const __attribute__((address_space(1))) void*)(esrc + off),
                    (__attribute__((address_space(3))) void*)((char*)ehS + off), 16, 0, 0);
                __builtin_amdgcn_global_load_lds(
                    (const __attribute__((address_space(1))) void*)(lsrc + off),
                    (__attribute__((address_space(3))) void*)((char*)elS + off), 16, 0, 0);
            }
            if (tid < 128) {   // wave-uniform (waves 0,1): remaining 2048 B
                size_t off = 16384 + (size_t)tid * 16;
                __builtin_amdgcn_global_load_lds(
                    (const __attribute__((address_space(1))) void*)(esrc + off),
                    (__attribute__((address_space(3))) void*)((char*)ehS + off), 16, 0, 0);
                __builtin_amdgcn_global_load_lds(
                    (const __attribute__((address_space(1))) void*)(lsrc + off),
                    (__attribute__((address_space(3))) void*)((char*)elS + off), 16, 0, 0);
            }
            if (tid < NCHUNK / 4)
                reinterpret_cast<float4*>(nrmL)[tid] =
                    reinterpret_cast<const float4*>(norms)[c * (NCHUNK / 4) + tid];
        }
        __syncthreads();   // barrier drains vmcnt -> LDS valid

#pragma unroll
        for (int ct = 0; ct < 8; ++ct) {
            int ar = (ct * 16 + c16) * LSTR + j * 8;
            short8v aeh0 = *reinterpret_cast<const short8v*>(&ehS[ar]);
            short8v aeh1 = *reinterpret_cast<const short8v*>(&ehS[ar + 32]);
            short8v ael0 = *reinterpret_cast<const short8v*>(&elS[ar]);
            short8v ael1 = *reinterpret_cast<const short8v*>(&elS[ar + 32]);
            float4 nr = *reinterpret_cast<const float4*>(&nrmL[ct * 16 + j * 4]);
            float nra[4] = {nr.x, nr.y, nr.z, nr.w};
            int kg0 = c * NCHUNK + ct * 16 + j * 4;
#pragma unroll
            for (int p = 0; p < 2; ++p) {
                f32x4 acc = {0.f, 0.f, 0.f, 0.f};
                acc = __builtin_amdgcn_mfma_f32_16x16x32_bf16(aeh0, bzh[p][0], acc, 0, 0, 0);
                acc = __builtin_amdgcn_mfma_f32_16x16x32_bf16(aeh1, bzh[p][1], acc, 0, 0, 0);
                acc = __builtin_amdgcn_mfma_f32_16x16x32_bf16(aeh0, bzl[p][0], acc, 0, 0, 0);
                acc = __builtin_amdgcn_mfma_f32_16x16x32_bf16(aeh1, bzl[p][1], acc, 0, 0, 0);
                acc = __builtin_amdgcn_mfma_f32_16x16x32_bf16(ael0, bzh[p][0], acc, 0, 0, 0);
                acc = __builtin_amdgcn_mfma_f32_16x16x32_bf16(ael1, bzh[p][1], acc, 0, 0, 0);
#pragma unroll
                for (int r = 0; r < 4; ++r) {
                    float s = fmaf(-2.0f, acc[r], nra[r]);   // accuracy-only path
                    int kg = kg0 + r;
                    bool lt1 = s < m1[p];
                    float nm2 = lt1 ? m1[p] : fminf(s, m2[p]);
                    i1[p] = lt1 ? kg : i1[p];
                    m1[p] = lt1 ? s : m1[p];
                    m2[p] = nm2;
                }
            }
        }
    }

    // ---- butterfly merge + compacting store ----
#pragma unroll
    for (int p = 0; p < 2; ++p) {
        float a1 = m1[p], a2 = m2[p]; int ai = i1[p];
#pragma unroll
        for (int off = 16; off <= 32; off <<= 1) {
            float o1 = __shfl_xor(a1, off, 64);
            float o2 = __shfl_xor(a2, off, 64);
            int   oi = __shfl_xor(ai, off, 64);
            float hi = fmaxf(a1, o1);
            bool take = o1 < a1;                 // ties keep own (tie => flagged anyway)
            ai = take ? oi : ai;
            a1 = take ? o1 : a1;
            a2 = fminf(hi, fminf(a2, o2));
        }
        int  ptg    = base + (2 * w + p) * 16 + c16;
        bool writer = (j == 0) && (ptg < n);
        bool flag   = writer && (a2 - a1 <= EPS_GAP);
        unsigned long long m = __ballot(flag);
        int abase = 0;
        if (m) {
            int leader = __ffsll(m) - 1;
            if (l == leader) abase = atomicAdd(cnt, __popcll(m));
            abase = __shfl(abase, leader, 64);
        }
        if (writer) {
            int val = ai;
            if (flag) {
                int rank = __popcll(m & ((1ull << l) - 1ull));
                int slot = abase + rank;
                if (slot < cap) list[slot] = ptg;       // worklist path
                else            val |= (int)0x80000000; // overflow fallback
            }
            out[ptg] = val;
        }
    }
}

// ---------- Pass 1 LEGACY (R13 verbatim): used only if ws too small ----------
__global__ __launch_bounds__(256)
void vq_pass1_legacy(const float* __restrict__ z, const float* __restrict__ cb,
                     const float* __restrict__ norms, int* __restrict__ out,
                     int* __restrict__ cnt, int* __restrict__ list, int cap, int n) {
    __shared__ unsigned short zhS[BM * LSTR];
    __shared__ unsigned short zlS[BM * LSTR];
    __shared__ unsigned short ehS[NCHUNK * LSTR];
    __shared__ unsigned short elS[NCHUNK * LSTR];
    __shared__ float nrmL[NCHUNK];

    const int tid  = threadIdx.x;
    const int l    = tid & 63;
    const int w    = tid >> 6;
    const int j    = l >> 4;
    const int c16  = l & 15;
    const int base = blockIdx.x * BM;

    const float4* z4 = reinterpret_cast<const float4*>(z);
#pragma unroll
    for (int rep = 0; rep < 8; ++rep) {
        int flat = rep * THREADS + tid;
        int pt   = flat >> 4;
        int dblk = flat & 15;
        int gp = base + pt; if (gp >= n) gp = n - 1;
        float4 v = z4[(size_t)gp * 16 + dblk];
        ushort4 h, lo;
        split2(v.x, h.x, lo.x); split2(v.y, h.y, lo.y);
        split2(v.z, h.z, lo.z); split2(v.w, h.w, lo.w);
        *reinterpret_cast<ushort4*>(&zhS[pt * LSTR + dblk * 4]) = h;
        *reinterpret_cast<ushort4*>(&zlS[pt * LSTR + dblk * 4]) = lo;
    }
    __syncthreads();

    short8v bzh[2][2], bzl[2][2];
#pragma unroll
    for (int p = 0; p < 2; ++p) {
        int pr = ((2 * w + p) * 16 + c16) * LSTR;
#pragma unroll
        for (int h = 0; h < 2; ++h) {
            int off = pr + h * 32 + j * 8;
            bzh[p][h] = *reinterpret_cast<const short8v*>(&zhS[off]);
            bzl[p][h] = *reinterpret_cast<const short8v*>(&zlS[off]);
        }
    }

    float m1[2] = {INFINITY, INFINITY};
    float m2[2] = {INFINITY, INFINITY};
    int   i1[2] = {0, 0};

    for (int c = 0; c < 4; ++c) {
        __syncthreads();
        const float4* cb4 = reinterpret_cast<const float4*>(cb);
#pragma unroll
        for (int rep = 0; rep < 8; ++rep) {
            int flat = rep * THREADS + tid;
            int code = flat >> 4;
            int dblk = flat & 15;
            float4 v = cb4[(size_t)(c * NCHUNK + code) * 16 + dblk];
            ushort4 h, lo;
            split2(v.x, h.x, lo.x); split2(v.y, h.y, lo.y);
            split2(v.z, h.z, lo.z); split2(v.w, h.w, lo.w);
            *reinterpret_cast<ushort4*>(&ehS[code * LSTR + dblk * 4]) = h;
            *reinterpret_cast<ushort4*>(&elS[code * LSTR + dblk * 4]) = lo;
        }
        if (tid < NCHUNK / 4)
            reinterpret_cast<float4*>(nrmL)[tid] =
                reinterpret_cast<const float4*>(norms)[c * (NCHUNK / 4) + tid];
        __syncthreads();

#pragma unroll
        for (int ct = 0; ct < 8; ++ct) {
            int ar = (ct * 16 + c16) * LSTR + j * 8;
            short8v aeh0 = *reinterpret_cast<const short8v*>(&ehS[ar]);
            short8v aeh1 = *reinterpret_cast<const short8v*>(&ehS[ar + 32]);
            short8v ael0 = *reinterpret_cast<const short8v*>(&elS[ar]);
            short8v ael1 = *reinterpret_cast<const short8v*>(&elS[ar + 32]);
            float4 nr = *reinterpret_cast<const float4*>(&nrmL[ct * 16 + j * 4]);
            float nra[4] = {nr.x, nr.y, nr.z, nr.w};
            int kg0 = c * NCHUNK + ct * 16 + j * 4;
#pragma unroll
            for (int p = 0; p < 2; ++p) {
                f32x4 acc = {0.f, 0.f, 0.f, 0.f};
                acc = __builtin_amdgcn_mfma_f32_16x16x32_bf16(aeh0, bzh[p][0], acc, 0, 0, 0);
                acc = __builtin_amdgcn_mfma_f32_16x16x32_bf16(aeh1, bzh[p][1], acc, 0, 0, 0);
                acc = __builtin_amdgcn_mfma_f32_16x16x32_bf16(aeh0, bzl[p][0], acc, 0, 0, 0);
                acc = __builtin_amdgcn_mfma_f32_16x16x32_bf16(aeh1, bzl[p][1], acc, 0, 0, 0);
                acc = __builtin_amdgcn_mfma_f32_16x16x32_bf16(ael0, bzh[p][0], acc, 0, 0, 0);
                acc = __builtin_amdgcn_mfma_f32_16x16x32_bf16(ael1, bzh[p][1], acc, 0, 0, 0);
#pragma unroll
                for (int r = 0; r < 4; ++r) {
                    float s = fmaf(-2.0f, acc[r], nra[r]);
                    int kg = kg0 + r;
                    bool lt1 = s < m1[p];
                    float nm2 = lt1 ? m1[p] : fminf(s, m2[p]);
                    i1[p] = lt1 ? kg : i1[p];
                    m1[p] = lt1 ? s : m1[p];
                    m2[p] = nm2;
                }
            }
        }
    }

#pragma unroll
    for (int p = 0; p < 2; ++p) {
        float a1 = m1[p], a2 = m2[p]; int ai = i1[p];
#pragma unroll
        for (int off = 16; off <= 32; off <<= 1) {
            float o1 = __shfl_xor(a1, off, 64);
            float o2 = __shfl_xor(a2, off, 64);
            int   oi = __shfl_xor(ai, off, 64);
            float hi = fmaxf(a1, o1);
            bool take = o1 < a1;
            ai = take ? oi : ai;
            a1 = take ? o1 : a1;
            a2 = fminf(hi, fminf(a2, o2));
        }
        int  ptg    = base + (2 * w + p) * 16 + c16;
        bool writer = (j == 0) && (ptg < n);
        bool flag   = writer && (a2 - a1 <= EPS_GAP);
        unsigned long long m = __ballot(flag);
        int abase = 0;
        if (m) {
            int leader = __ffsll(m) - 1;
            if (l == leader) abase = atomicAdd(cnt, __popcll(m));
            abase = __shfl(abase, leader, 64);
        }
        if (writer) {
            int val = ai;
            if (flag) {
                int rank = __popcll(m & ((1ull << l) - 1ull));
                int slot = abase + rank;
                if (slot < cap) list[slot] = ptg;
                else            val |= (int)0x80000000;
            }
            out[ptg] = val;
        }
    }
}

// ---------- Pass 2: one wave per flagged point (grid-strided worklist) ----------
__device__ __forceinline__ void vq_rescan_point(
        const float* __restrict__ z, const float* __restrict__ cb,
        const float* __restrict__ norms, int* __restrict__ out,
        int pt, int lane) {
    float zr[D_DIM];
    const float4* zp = reinterpret_cast<const float4*>(z + (size_t)pt * D_DIM);
#pragma unroll
    for (int i = 0; i < 16; ++i) {
        float4 q = zp[i];
        zr[4*i+0]=q.x; zr[4*i+1]=q.y; zr[4*i+2]=q.z; zr[4*i+3]=q.w;
    }
    const float sz = np_sumsq64(zr);           // FROZEN tree
    float best = INFINITY; int bi = 0x7FFFFFFF;
#pragma unroll 1
    for (int r = 0; r < 8; ++r) {              // 8 codes/lane, SEQUENTIAL (no spill)
        const float4* e4 = reinterpret_cast<const float4*>(cb) +
                           ((size_t)(lane * 8 + r) << 4);
        float a = 0.f;
#pragma unroll
        for (int g = 0; g < 16; ++g) {         // FROZEN ascending-d chain
            float4 q = e4[g];
            a = fmaf(zr[4*g+0], q.x, a);
            a = fmaf(zr[4*g+1], q.y, a);
            a = fmaf(zr[4*g+2], q.z, a);
            a = fmaf(zr[4*g+3], q.w, a);
        }
        float s = __fadd_rn(__fsub_rn(sz, __fmul_rn(2.0f, a)),
                            norms[lane * 8 + r]);
        if (s < best) { best = s; bi = lane * 8 + r; }
    }
#pragma unroll
    for (int off = 1; off < 64; off <<= 1) {   // (value, index) first-min reduce
        float os = __shfl_xor(best, off, 64);
        int   ok = __shfl_xor(bi, off, 64);
        if (os < best || (os == best && ok < bi)) { best = os; bi = ok; }
    }
    if (lane == 0) out[pt] = bi;
}

__global__ __launch_bounds__(256)
void vq_cleanup_kernel(const float* __restrict__ z, const float* __restrict__ cb,
                       const float* __restrict__ norms,
                       const int* __restrict__ cnt, const int* __restrict__ list,
                       int cap, int* __restrict__ out, int n) {
    const int lane   = threadIdx.x & 63;
    const int wid    = (blockIdx.x * blockDim.x + threadIdx.x) >> 6;
    const int nwaves = (gridDim.x * blockDim.x) >> 6;

    int total = *cnt;
    int lim   = total < cap ? total : cap;
    for (int i = wid; i < lim; i += nwaves)
        vq_rescan_point(z, cb, norms, out, list[i], lane);

    if (total > cap) {   // overflow fallback: scan out[] for bit-31 flags
        for (int b = wid * 64; b < n; b += nwaves * 64) {
            int t = b + lane;
            int v = (t < n) ? out[t] : 0;
            unsigned long long m = __ballot(v < 0);
            while (m) {
                int bb = __ffsll(m) - 1;
                m &= m - 1ull;
                vq_rescan_point(z, cb, norms, out, b + bb, lane);
            }
        }
    }
}

extern "C" void kernel_launch(void* const* d_in, const int* in_sizes, int n_in,
                              void* d_out, int out_size, void* d_ws, size_t ws_size,
                              hipStream_t stream) {
    const float* z  = (const float*)d_in[0];
    const float* cb = (const float*)d_in[1];
    int n = in_sizes[0] / D_DIM;           // 131072 points
    float* norms = (float*)d_ws;
    int*   cnt   = (int*)((char*)d_ws + WS_CNT_OFF);
    int* out = (int*)d_out;

    bool fast = ws_size >= (size_t)WS_LIST_OFF + 4096;   // presplit region + some list
    vq_prep_kernel<<<(K_CODES + 255) / 256, 256, 0, stream>>>(cb, norms, fast ? 1 : 0);

    if (fast) {
        const unsigned short* eh = (const unsigned short*)((char*)d_ws + WS_EH_OFF);
        const unsigned short* el = (const unsigned short*)((char*)d_ws + WS_EL_OFF);
        int* list = (int*)((char*)d_ws + WS_LIST_OFF);
        int  cap  = (int)((ws_size - WS_LIST_OFF) / 4);
        vq_pass1_fast<<<(n + BM - 1) / BM, THREADS, 0, stream>>>(
            z, eh, el, norms, out, cnt, list, cap, n);
        vq_cleanup_kernel<<<512, 256, 0, stream>>>(z, cb, norms, cnt, list, cap, out, n);
    } else {
        int* list = (int*)d_ws + 513;
        int  cap  = (int)(ws_size / 4) - 513; if (cap < 0) cap = 0;
        vq_pass1_legacy<<<(n + BM - 1) / BM, THREADS, 0, stream>>>(
            z, cb, norms, out, cnt, list, cap, n);
        vq_cleanup_kernel<<<512, 256, 0, stream>>>(z, cb, norms, cnt, list, cap, out, n);
    }
}